// Round 1
// baseline (1895.781 us; speedup 1.0000x reference)
//
#include <hip/hip_runtime.h>

#define NPTS 100000
#define INC 256
#define WID 104
#define WSC 416
#define KOFF 27
#define EPSV 1e-5f

typedef unsigned short u16;
typedef float f32x4 __attribute__((ext_vector_type(4)));
typedef short s16x8 __attribute__((ext_vector_type(8)));

__device__ __forceinline__ u16 f2bf(float f) {
  unsigned u = __builtin_bit_cast(unsigned, f);
  u += 0x7FFFu + ((u >> 16) & 1u);
  return (u16)(u >> 16);
}
__device__ __forceinline__ float bf2f(u16 h) {
  unsigned u = ((unsigned)h) << 16;
  return __builtin_bit_cast(float, u);
}
__device__ __forceinline__ void mfma16(f32x4& d, s16x8 a, s16x8 b) {
  asm("v_mfma_f32_16x16x32_bf16 %0, %1, %2, %0" : "+v"(d) : "v"(a), "v"(b));
}

// ---------------- weight prep ----------------
__global__ __launch_bounds__(256) void k_prep_w1w3(const float* __restrict__ w1,
    const float* __restrict__ w3, u16* __restrict__ w1t, u16* __restrict__ w3t) {
  int i = blockIdx.x * 256 + threadIdx.x;
  if (i < 416 * 256) {
    int n = i >> 8, k = i & 255;
    w1t[i] = f2bf(w1[(size_t)k * WSC + n]);
  } else if (i < 2 * 416 * 256) {
    int o = i - 416 * 256;
    int n = o / WSC, k = o - n * WSC;
    w3t[o] = f2bf(w3[(size_t)k * INC + n]);
  }
}

__global__ __launch_bounds__(256) void k_prep_wc(const float* __restrict__ wc,
                                                 u16* __restrict__ wct) {
  __shared__ float w[WID * WID];
  int b = blockIdx.x, t = threadIdx.x;
  const float* s = wc + (size_t)b * WID * WID;
  for (int i = t; i < WID * WID; i += 256) w[i] = s[i];
  __syncthreads();
  u16* d = wct + (size_t)b * 112 * 128;
  for (int o = t; o < 112 * 128; o += 256) {
    int n = o >> 7, kin = o & 127;
    float v = (n < WID && kin < WID) ? w[kin * WID + n] : 0.f;
    d[o] = f2bf(v);
  }
}

__global__ void k_zero(float* p, int n) {
  for (int i = blockIdx.x * 256 + threadIdx.x; i < n; i += gridDim.x * 256) p[i] = 0.f;
}

// ---------------- GEMM1: x[N,256] @ W1 -> Y1[N,416] bf16 ----------------
__global__ __launch_bounds__(256) void k_gemm1(const float* __restrict__ x,
                                               const u16* __restrict__ w1t,
                                               u16* __restrict__ y1) {
  __shared__ s16x8 AlV[128 * 8];   // 128 rows x 64 bf16, XOR-swizzled
  __shared__ s16x8 BlV[112 * 8];
  char* Al = (char*)AlV;
  char* Bl = (char*)BlV;
  const int t = threadIdx.x;
  const int rowbase = blockIdx.x * 128;
  const int cb = blockIdx.y;
  const int lane = t & 63, wv = t >> 6, lr = lane & 15, lg = lane >> 4;
  const f32x4 fz = {0.f, 0.f, 0.f, 0.f};
  f32x4 acc[2][7];
#pragma unroll
  for (int i = 0; i < 2; ++i)
#pragma unroll
    for (int j = 0; j < 7; ++j) acc[i][j] = fz;

  for (int st = 0; st < 4; ++st) {
    if (st) __syncthreads();
#pragma unroll
    for (int it = 0; it < 4; ++it) {
      int task = t + it * 256;
      int r = task >> 3, c = task & 7;
      int gr = rowbase + r;
      s16x8 h = {0, 0, 0, 0, 0, 0, 0, 0};
      if (gr < NPTS) {
        const f32x4* s = (const f32x4*)(x + (size_t)gr * INC + st * 64 + c * 8);
        f32x4 v0 = s[0], v1 = s[1];
#pragma unroll
        for (int j = 0; j < 4; ++j) {
          h[j] = (short)f2bf(v0[j]);
          h[4 + j] = (short)f2bf(v1[j]);
        }
      }
      int ad = (r * 128 + c * 16) ^ ((r & 7) << 4);
      *(s16x8*)(Al + ad) = h;
    }
#pragma unroll
    for (int it = 0; it < 4; ++it) {
      int task = t + it * 256;
      if (task < 896) {
        int r = task >> 3, c = task & 7;
        s16x8 h = {0, 0, 0, 0, 0, 0, 0, 0};
        if (r < WID)
          h = *(const s16x8*)(w1t + (size_t)(cb * WID + r) * 256 + st * 64 + c * 8);
        int ad = (r * 128 + c * 16) ^ ((r & 7) << 4);
        *(s16x8*)(Bl + ad) = h;
      }
    }
    __syncthreads();
#pragma unroll
    for (int kc = 0; kc < 2; ++kc) {
      const int colb = kc * 64 + lg * 16;
      s16x8 a[2], b[7];
#pragma unroll
      for (int mt = 0; mt < 2; ++mt) {
        int r = wv * 32 + mt * 16 + lr;
        a[mt] = *(const s16x8*)(Al + ((r * 128 + colb) ^ ((r & 7) << 4)));
      }
#pragma unroll
      for (int ct = 0; ct < 7; ++ct) {
        int r = ct * 16 + lr;
        b[ct] = *(const s16x8*)(Bl + ((r * 128 + colb) ^ ((r & 7) << 4)));
      }
#pragma unroll
      for (int mt = 0; mt < 2; ++mt)
#pragma unroll
        for (int ct = 0; ct < 7; ++ct) mfma16(acc[mt][ct], a[mt], b[ct]);
    }
  }
#pragma unroll
  for (int mt = 0; mt < 2; ++mt)
#pragma unroll
    for (int ct = 0; ct < 7; ++ct)
#pragma unroll
      for (int j = 0; j < 4; ++j) {
        int r = rowbase + wv * 32 + mt * 16 + lg * 4 + j;
        int cl = ct * 16 + lr;
        if (r < NPTS && cl < WID)
          y1[(size_t)r * WSC + cb * WID + cl] = f2bf(acc[mt][ct][j]);
      }
}

// ---------------- sparse conv: Z[n] = sum_k src[nbr[n,k]] @ Wk ----------------
__global__ __launch_bounds__(256) void k_conv(const u16* __restrict__ src, int srcStride,
                                              const int* __restrict__ nbr,
                                              const u16* __restrict__ wct,
                                              u16* __restrict__ z) {
  __shared__ int idxl[128 * KOFF];
  __shared__ s16x8 AlV[128 * 16];  // 128 x 128 bf16 (K pad 104->128)
  __shared__ s16x8 BlV[112 * 16];
  char* Al = (char*)AlV;
  char* Bl = (char*)BlV;
  const int t = threadIdx.x;
  const int rowbase = blockIdx.x * 128;
  const int lane = t & 63, wv = t >> 6, lr = lane & 15, lg = lane >> 4;

  const int ibase = rowbase * KOFF;
  for (int i = t; i < 128 * KOFF; i += 256)
    idxl[i] = (ibase + i < NPTS * KOFF) ? nbr[ibase + i] : NPTS;

  const f32x4 fz = {0.f, 0.f, 0.f, 0.f};
  f32x4 acc[2][7];
#pragma unroll
  for (int i = 0; i < 2; ++i)
#pragma unroll
    for (int j = 0; j < 7; ++j) acc[i][j] = fz;

  for (int k = 0; k < KOFF; ++k) {
    __syncthreads();
    // gather A: 128 rows x 16 chunks (13 data + 3 zero pad)
#pragma unroll
    for (int it = 0; it < 8; ++it) {
      int task = t + it * 256;
      int r = task >> 4, c = task & 15;
      s16x8 h = {0, 0, 0, 0, 0, 0, 0, 0};
      if (c < 13) {
        int ridx = idxl[r * KOFF + k];
        if (ridx < NPTS)
          h = *(const s16x8*)(src + (size_t)ridx * srcStride + c * 8);
      }
      int ad = (r * 256 + c * 16) ^ ((r & 7) << 4);
      *(s16x8*)(Al + ad) = h;
    }
    // B: 112 rows x 16 chunks (pre-padded)
#pragma unroll
    for (int it = 0; it < 7; ++it) {
      int task = t + it * 256;
      int r = task >> 4, c = task & 15;
      s16x8 h = *(const s16x8*)(wct + ((size_t)k * 112 + r) * 128 + c * 8);
      int ad = (r * 256 + c * 16) ^ ((r & 7) << 4);
      *(s16x8*)(Bl + ad) = h;
    }
    __syncthreads();
#pragma unroll
    for (int kc = 0; kc < 4; ++kc) {
      const int colb = kc * 64 + lg * 16;
      s16x8 a[2], b[7];
#pragma unroll
      for (int mt = 0; mt < 2; ++mt) {
        int r = wv * 32 + mt * 16 + lr;
        a[mt] = *(const s16x8*)(Al + ((r * 256 + colb) ^ ((r & 7) << 4)));
      }
#pragma unroll
      for (int ct = 0; ct < 7; ++ct) {
        int r = ct * 16 + lr;
        b[ct] = *(const s16x8*)(Bl + ((r * 256 + colb) ^ ((r & 7) << 4)));
      }
#pragma unroll
      for (int mt = 0; mt < 2; ++mt)
#pragma unroll
        for (int ct = 0; ct < 7; ++ct) mfma16(acc[mt][ct], a[mt], b[ct]);
    }
  }
#pragma unroll
  for (int mt = 0; mt < 2; ++mt)
#pragma unroll
    for (int ct = 0; ct < 7; ++ct)
#pragma unroll
      for (int j = 0; j < 4; ++j) {
        int r = rowbase + wv * 32 + mt * 16 + lg * 4 + j;
        int cl = ct * 16 + lr;
        if (r < NPTS && cl < WID)
          z[(size_t)r * WID + cl] = f2bf(acc[mt][ct][j]);
      }
}

// ---------------- GEMM3: cat[N,416] @ W3 -> out[N,256] fp32 ----------------
__global__ __launch_bounds__(256) void k_gemm3(const u16* __restrict__ sp0,
    const u16* __restrict__ sp1, const u16* __restrict__ sp2,
    const u16* __restrict__ y1, const u16* __restrict__ w3t,
    float* __restrict__ out) {
  __shared__ s16x8 AlV[128 * 8];
  __shared__ s16x8 BlV[128 * 8];
  char* Al = (char*)AlV;
  char* Bl = (char*)BlV;
  const int t = threadIdx.x;
  const int rowbase = blockIdx.x * 128;
  const int cb = blockIdx.y;
  const int lane = t & 63, wv = t >> 6, lr = lane & 15, lg = lane >> 4;
  const int wr = wv >> 1, wc = wv & 1;
  const f32x4 fz = {0.f, 0.f, 0.f, 0.f};
  f32x4 acc[4][4];
#pragma unroll
  for (int i = 0; i < 4; ++i)
#pragma unroll
    for (int j = 0; j < 4; ++j) acc[i][j] = fz;

  for (int st = 0; st < 7; ++st) {  // K padded 416 -> 448, stages of 64
    if (st) __syncthreads();
#pragma unroll
    for (int it = 0; it < 4; ++it) {
      int task = t + it * 256;
      int r = task >> 3, c = task & 7;
      int gr = rowbase + r;
      int gc = st * 8 + c;  // global 16B chunk of the virtual cat row
      s16x8 h = {0, 0, 0, 0, 0, 0, 0, 0};
      if (gr < NPTS && gc < 52) {
        int p = gc / 13;
        int cc8 = (gc - p * 13) * 8;
        const u16* s;
        if (p == 0) s = sp0 + (size_t)gr * WID + cc8;
        else if (p == 1) s = sp1 + (size_t)gr * WID + cc8;
        else if (p == 2) s = sp2 + (size_t)gr * WID + cc8;
        else s = y1 + (size_t)gr * WSC + 312 + cc8;
        h = *(const s16x8*)s;
      }
      int ad = (r * 128 + c * 16) ^ ((r & 7) << 4);
      *(s16x8*)(Al + ad) = h;
    }
#pragma unroll
    for (int it = 0; it < 4; ++it) {
      int task = t + it * 256;
      int r = task >> 3, c = task & 7;
      int gk = st * 64 + c * 8;
      s16x8 h = {0, 0, 0, 0, 0, 0, 0, 0};
      if (gk < WSC)
        h = *(const s16x8*)(w3t + (size_t)(cb * 128 + r) * WSC + gk);
      int ad = (r * 128 + c * 16) ^ ((r & 7) << 4);
      *(s16x8*)(Bl + ad) = h;
    }
    __syncthreads();
#pragma unroll
    for (int kc = 0; kc < 2; ++kc) {
      const int colb = kc * 64 + lg * 16;
      s16x8 a[4], b[4];
#pragma unroll
      for (int mt = 0; mt < 4; ++mt) {
        int r = wr * 64 + mt * 16 + lr;
        a[mt] = *(const s16x8*)(Al + ((r * 128 + colb) ^ ((r & 7) << 4)));
      }
#pragma unroll
      for (int ct = 0; ct < 4; ++ct) {
        int r = wc * 64 + ct * 16 + lr;
        b[ct] = *(const s16x8*)(Bl + ((r * 128 + colb) ^ ((r & 7) << 4)));
      }
#pragma unroll
      for (int mt = 0; mt < 4; ++mt)
#pragma unroll
        for (int ct = 0; ct < 4; ++ct) mfma16(acc[mt][ct], a[mt], b[ct]);
    }
  }
#pragma unroll
  for (int mt = 0; mt < 4; ++mt)
#pragma unroll
    for (int ct = 0; ct < 4; ++ct)
#pragma unroll
      for (int j = 0; j < 4; ++j) {
        int r = rowbase + wr * 64 + mt * 16 + lg * 4 + j;
        int c = cb * 128 + wc * 64 + ct * 16 + lr;
        if (r < NPTS) out[(size_t)r * INC + c] = acc[mt][ct][j];
      }
}

// ---------------- column stats (sum, sumsq) ----------------
template <int ISBF>
__global__ __launch_bounds__(256) void k_colstats(const void* __restrict__ srcv, int C,
                                                  float* __restrict__ st) {
  const int RPB = 2048;
  int t = threadIdx.x;
  int c = blockIdx.y * 64 + (t & 63);
  int rend = (int)((blockIdx.x + 1) * RPB);
  if (rend > NPTS) rend = NPTS;
  float s = 0.f, q = 0.f;
  if (c < C) {
    for (int r = (int)(blockIdx.x * RPB) + (t >> 6); r < rend; r += 4) {
      float v;
      if (ISBF) v = bf2f(((const u16*)srcv)[(size_t)r * C + c]);
      else v = ((const float*)srcv)[(size_t)r * C + c];
      s += v;
      q += v * v;
    }
  }
  __shared__ float ls[256], lq[256];
  ls[t] = s;
  lq[t] = q;
  __syncthreads();
  if (t < 64) {
    s = ls[t] + ls[t + 64] + ls[t + 128] + ls[t + 192];
    q = lq[t] + lq[t + 64] + lq[t + 128] + lq[t + 192];
    if (c < C) {
      atomicAdd(&st[c], s);
      atomicAdd(&st[C + c], q);
    }
  }
}

__global__ __launch_bounds__(512) void k_finstats(float* st, const float* __restrict__ g,
                                                  const float* __restrict__ b, int C) {
  int c = threadIdx.x;
  if (c < C) {
    float m = st[c] * (1.f / NPTS);
    float var = st[C + c] * (1.f / NPTS) - m * m;
    float rs = rsqrtf(var + EPSV);
    float sc = rs * g[c];
    st[2 * C + c] = sc;
    st[3 * C + c] = b[c] - m * sc;
  }
}

// ---------------- BN apply kernels ----------------
__global__ __launch_bounds__(256) void k_bnrelu1(u16* __restrict__ y,
    const float* __restrict__ scale, const float* __restrict__ shift) {
  const int total = NPTS * 52;
  for (int i = blockIdx.x * 256 + threadIdx.x; i < total; i += gridDim.x * 256) {
    int r = i / 52, cc = i - r * 52;
    s16x8 v = *(s16x8*)(y + (size_t)r * WSC + cc * 8);
#pragma unroll
    for (int j = 0; j < 8; ++j) {
      int c = cc * 8 + j;
      float xv = bf2f((u16)v[j]) * scale[c] + shift[c];
      v[j] = (short)f2bf(fmaxf(xv, 0.f));
    }
    *(s16x8*)(y + (size_t)r * WSC + cc * 8) = v;
  }
}

__global__ __launch_bounds__(256) void k_bnrelu_conv(const u16* __restrict__ z,
    const float* __restrict__ scale, const float* __restrict__ shift,
    u16* __restrict__ sp, const u16* __restrict__ y1, int sliceOff,
    u16* __restrict__ spin, int writeSpin) {
  const int total = NPTS * 13;
  for (int i = blockIdx.x * 256 + threadIdx.x; i < total; i += gridDim.x * 256) {
    int r = i / 13, cc = i - r * 13;
    s16x8 v = *(const s16x8*)(z + (size_t)r * WID + cc * 8);
    s16x8 o;
#pragma unroll
    for (int j = 0; j < 8; ++j) {
      int c = cc * 8 + j;
      float xv = bf2f((u16)v[j]) * scale[c] + shift[c];
      o[j] = (short)f2bf(fmaxf(xv, 0.f));
    }
    *(s16x8*)(sp + (size_t)r * WID + cc * 8) = o;
    if (writeSpin) {
      s16x8 u = *(const s16x8*)(y1 + (size_t)r * WSC + sliceOff + cc * 8);
      s16x8 w;
#pragma unroll
      for (int j = 0; j < 8; ++j)
        w[j] = (short)f2bf(bf2f((u16)o[j]) + bf2f((u16)u[j]));
      *(s16x8*)(spin + (size_t)r * WID + cc * 8) = w;
    }
  }
}

__global__ __launch_bounds__(256) void k_final(float* __restrict__ y,
    const float* __restrict__ scale, const float* __restrict__ shift,
    const float* __restrict__ x) {
  const int total = NPTS * 64;
  for (int i = blockIdx.x * 256 + threadIdx.x; i < total; i += gridDim.x * 256) {
    int r = i >> 6, cc = i & 63;
    f32x4 v = *(f32x4*)(y + (size_t)r * INC + cc * 4);
    f32x4 xf = *(const f32x4*)(x + (size_t)r * INC + cc * 4);
#pragma unroll
    for (int j = 0; j < 4; ++j) {
      int c = cc * 4 + j;
      v[j] = fmaxf(v[j] * scale[c] + shift[c] + xf[j], 0.f);
    }
    *(f32x4*)(y + (size_t)r * INC + cc * 4) = v;
  }
}

// ---------------- launch ----------------
extern "C" void kernel_launch(void* const* d_in, const int* in_sizes, int n_in,
                              void* d_out, int out_size, void* d_ws, size_t ws_size,
                              hipStream_t stream) {
  const float* x  = (const float*)d_in[0];
  const int* nbr  = (const int*)d_in[1];
  const float* W1 = (const float*)d_in[2];
  const float* g1 = (const float*)d_in[3];
  const float* b1 = (const float*)d_in[4];
  const float* Wc = (const float*)d_in[5];
  const float* gc = (const float*)d_in[6];
  const float* bc = (const float*)d_in[7];
  const float* W3 = (const float*)d_in[8];
  const float* g3 = (const float*)d_in[9];
  const float* b3 = (const float*)d_in[10];
  float* out = (float*)d_out;

  char* ws = (char*)d_ws;
  size_t off = 0;
  auto alloc = [&](size_t n) {
    char* p = ws + off;
    off += (n + 255) & ~(size_t)255;
    return p;
  };
  u16* W1T = (u16*)alloc(416 * 256 * 2);
  u16* W3T = (u16*)alloc(256 * 416 * 2);
  u16* WCT = (u16*)alloc((size_t)3 * 27 * 112 * 128 * 2);
  u16* Y1  = (u16*)alloc((size_t)NPTS * WSC * 2);
  u16* Z   = (u16*)alloc((size_t)NPTS * WID * 2);
  u16* SP0 = (u16*)alloc((size_t)NPTS * WID * 2);
  u16* SP1 = (u16*)alloc((size_t)NPTS * WID * 2);
  u16* SP2 = (u16*)alloc((size_t)NPTS * WID * 2);
  u16* SPIN = (u16*)alloc((size_t)NPTS * WID * 2);
  float* ST = (float*)alloc(3936 * 4);
  float* ST1 = ST;
  float* STC0 = ST + 1664;
  float* STC1 = ST + 2080;
  float* STC2 = ST + 2496;
  float* ST3 = ST + 2912;

  k_prep_w1w3<<<832, 256, 0, stream>>>(W1, W3, W1T, W3T);
  k_prep_wc<<<81, 256, 0, stream>>>(Wc, WCT);
  k_zero<<<16, 256, 0, stream>>>(ST, 3936);

  k_gemm1<<<dim3(782, 4), 256, 0, stream>>>(x, W1T, Y1);
  k_colstats<1><<<dim3(49, 7), 256, 0, stream>>>(Y1, WSC, ST1);
  k_finstats<<<1, 512, 0, stream>>>(ST1, g1, b1, WSC);
  k_bnrelu1<<<2048, 256, 0, stream>>>(Y1, ST1 + 832, ST1 + 1248);

  const size_t WCL = (size_t)27 * 112 * 128;
  // branch 0: input = out1[:, 0:104] (stride 416)
  k_conv<<<782, 256, 0, stream>>>(Y1, WSC, nbr, WCT, Z);
  k_colstats<1><<<dim3(49, 2), 256, 0, stream>>>(Z, WID, STC0);
  k_finstats<<<1, 512, 0, stream>>>(STC0, gc, bc, WID);
  k_bnrelu_conv<<<1024, 256, 0, stream>>>(Z, STC0 + 208, STC0 + 312, SP0, Y1, 104, SPIN, 1);
  // branch 1: input = sp0 + out1[:,104:208]
  k_conv<<<782, 256, 0, stream>>>(SPIN, WID, nbr, WCT + WCL, Z);
  k_colstats<1><<<dim3(49, 2), 256, 0, stream>>>(Z, WID, STC1);
  k_finstats<<<1, 512, 0, stream>>>(STC1, gc + 104, bc + 104, WID);
  k_bnrelu_conv<<<1024, 256, 0, stream>>>(Z, STC1 + 208, STC1 + 312, SP1, Y1, 208, SPIN, 1);
  // branch 2: input = sp1 + out1[:,208:312]
  k_conv<<<782, 256, 0, stream>>>(SPIN, WID, nbr, WCT + 2 * WCL, Z);
  k_colstats<1><<<dim3(49, 2), 256, 0, stream>>>(Z, WID, STC2);
  k_finstats<<<1, 512, 0, stream>>>(STC2, gc + 208, bc + 208, WID);
  k_bnrelu_conv<<<1024, 256, 0, stream>>>(Z, STC2 + 208, STC2 + 312, SP2, Y1, 0, SPIN, 0);

  k_gemm3<<<dim3(782, 2), 256, 0, stream>>>(SP0, SP1, SP2, Y1, W3T, out);
  k_colstats<0><<<dim3(49, 4), 256, 0, stream>>>(out, INC, ST3);
  k_finstats<<<1, 512, 0, stream>>>(ST3, g3, b3, INC);
  k_final<<<2048, 256, 0, stream>>>(out, ST3 + 512, ST3 + 768, x);
}

// Round 2
// 1888.990 us; speedup vs baseline: 1.0036x; 1.0036x over previous
//
#include <hip/hip_runtime.h>

#define NPTS 100000
#define INC 256
#define WID 104
#define WSC 416
#define KOFF 27
#define EPSV 1e-5f

typedef unsigned short u16;
typedef float f32x4 __attribute__((ext_vector_type(4)));
typedef short s16x8 __attribute__((ext_vector_type(8)));

__device__ __forceinline__ u16 f2bf(float f) {
  unsigned u = __builtin_bit_cast(unsigned, f);
  u += 0x7FFFu + ((u >> 16) & 1u);
  return (u16)(u >> 16);
}
__device__ __forceinline__ float bf2f(u16 h) {
  unsigned u = ((unsigned)h) << 16;
  return __builtin_bit_cast(float, u);
}
__device__ __forceinline__ void mfma16(f32x4& d, s16x8 a, s16x8 b) {
  asm("v_mfma_f32_16x16x32_bf16 %0, %1, %2, %0" : "+v"(d) : "v"(a), "v"(b));
}
__device__ __forceinline__ void rawbar() {
  __builtin_amdgcn_s_barrier();
  __builtin_amdgcn_sched_barrier(0);
}

// ---------------- weight prep ----------------
__global__ __launch_bounds__(256) void k_prep_w1w3(const float* __restrict__ w1,
    const float* __restrict__ w3, u16* __restrict__ w1t, u16* __restrict__ w3t) {
  int i = blockIdx.x * 256 + threadIdx.x;
  if (i < 416 * 256) {
    int n = i >> 8, k = i & 255;
    w1t[i] = f2bf(w1[(size_t)k * WSC + n]);
  } else if (i < 2 * 416 * 256) {
    int o = i - 416 * 256;
    int n = o / WSC, k = o - n * WSC;
    w3t[o] = f2bf(w3[(size_t)k * INC + n]);
  }
}

// WCT layout: [branch*27+k][112 rows=out-col (8 pad)][104 cols=k-in] bf16
__global__ __launch_bounds__(256) void k_prep_wc(const float* __restrict__ wc,
                                                 u16* __restrict__ wct) {
  __shared__ float w[WID * WID];
  int b = blockIdx.x, t = threadIdx.x;
  const float* s = wc + (size_t)b * WID * WID;
  for (int i = t; i < WID * WID; i += 256) w[i] = s[i];
  __syncthreads();
  u16* d = wct + (size_t)b * 112 * WID;
  for (int o = t; o < 112 * WID; o += 256) {
    int n = o / WID, kin = o - n * WID;
    d[o] = f2bf((n < WID) ? w[kin * WID + n] : 0.f);
  }
}

__global__ void k_init(float* __restrict__ st, u16* __restrict__ spxrow) {
  int i = blockIdx.x * 256 + threadIdx.x;
  if (i < 3936) st[i] = 0.f;
  else if (i < 3936 + 104) spxrow[i - 3936] = 0;
}

// ---------------- GEMM1: x[N,256] @ W1 -> Y1[N,416] bf16 raw + col stats ----------------
__global__ __launch_bounds__(256, 3) void k_gemm1(const float* __restrict__ x,
    const u16* __restrict__ w1t, u16* __restrict__ y1, float* __restrict__ stats) {
  __shared__ char Al[128 * 128];
  __shared__ char Bl[112 * 128];
  const int t = threadIdx.x, rowbase = blockIdx.x * 128, cb = blockIdx.y;
  const int lane = t & 63, wv = t >> 6, lr = lane & 15, lg = lane >> 4;
  const f32x4 fz = {0.f, 0.f, 0.f, 0.f};
  const s16x8 hz = {0, 0, 0, 0, 0, 0, 0, 0};
  f32x4 acc[2][7];
#pragma unroll
  for (int i = 0; i < 2; ++i)
#pragma unroll
    for (int j = 0; j < 7; ++j) acc[i][j] = fz;
  f32x4 pa[4][2];
  s16x8 pb[4];

  auto issue = [&](int st) {
#pragma unroll
    for (int it = 0; it < 4; ++it) {
      int task = t + it * 256, r = task >> 3, c = task & 7, gr = rowbase + r;
      if (gr < NPTS) {
        const f32x4* s = (const f32x4*)(x + (size_t)gr * INC + st * 64 + c * 8);
        pa[it][0] = s[0]; pa[it][1] = s[1];
      } else { pa[it][0] = fz; pa[it][1] = fz; }
      pb[it] = hz;
      if (task < 832)
        pb[it] = *(const s16x8*)(w1t + (size_t)(cb * WID + r) * INC + st * 64 + c * 8);
    }
  };
  auto writeT = [&]() {
#pragma unroll
    for (int it = 0; it < 4; ++it) {
      int task = t + it * 256, r = task >> 3, c = task & 7;
      s16x8 h;
#pragma unroll
      for (int j = 0; j < 4; ++j) { h[j] = (short)f2bf(pa[it][0][j]); h[4 + j] = (short)f2bf(pa[it][1][j]); }
      *(s16x8*)(Al + ((r * 128 + c * 16) ^ ((r & 7) << 4))) = h;
      if (task < 896) *(s16x8*)(Bl + ((r * 128 + c * 16) ^ ((r & 7) << 4))) = pb[it];
    }
  };
  auto compute = [&]() {
#pragma unroll
    for (int kc = 0; kc < 2; ++kc) {
      int co = kc * 64 + lg * 16;
      s16x8 a[2], b[7];
#pragma unroll
      for (int mt = 0; mt < 2; ++mt) {
        int r = wv * 32 + mt * 16 + lr;
        a[mt] = *(const s16x8*)(Al + ((r * 128 + co) ^ ((r & 7) << 4)));
      }
#pragma unroll
      for (int ct = 0; ct < 7; ++ct) {
        int r = ct * 16 + lr;
        b[ct] = *(const s16x8*)(Bl + ((r * 128 + co) ^ ((r & 7) << 4)));
      }
#pragma unroll
      for (int mt = 0; mt < 2; ++mt)
#pragma unroll
        for (int ct = 0; ct < 7; ++ct) mfma16(acc[mt][ct], a[mt], b[ct]);
    }
  };

  issue(0);
  for (int st = 0; st < 4; ++st) {
    writeT();
    __syncthreads();
    if (st < 3) issue(st + 1);
    compute();
    if (st < 3) rawbar();
  }
  // fused column stats (fp32 acc) + store
#pragma unroll
  for (int ct = 0; ct < 7; ++ct) {
    float s = 0.f, q = 0.f;
#pragma unroll
    for (int mt = 0; mt < 2; ++mt)
#pragma unroll
      for (int j = 0; j < 4; ++j) { float v = acc[mt][ct][j]; s += v; q += v * v; }
    s += __shfl_xor(s, 16); s += __shfl_xor(s, 32);
    q += __shfl_xor(q, 16); q += __shfl_xor(q, 32);
    int cl = ct * 16 + lr;
    if (cl < WID) {
      if (lg == 0) atomicAdd(&stats[cb * WID + cl], s);
      else if (lg == 1) atomicAdd(&stats[WSC + cb * WID + cl], q);
    }
  }
#pragma unroll
  for (int mt = 0; mt < 2; ++mt)
#pragma unroll
    for (int ct = 0; ct < 7; ++ct)
#pragma unroll
      for (int j = 0; j < 4; ++j) {
        int r = rowbase + wv * 32 + mt * 16 + lg * 4 + j;
        int cl = ct * 16 + lr;
        if (r < NPTS && cl < WID)
          y1[(size_t)r * WSC + cb * WID + cl] = f2bf(acc[mt][ct][j]);
      }
}

// ---------------- sparse conv: Z = sum_k gather(SPX)[nbr[:,k]] @ Wk, + col stats ----------------
__global__ __launch_bounds__(256, 3) void k_conv(const u16* __restrict__ src,
    const int* __restrict__ nbr, const u16* __restrict__ wct,
    u16* __restrict__ z, float* __restrict__ stats) {
  __shared__ char Al[128 * 208];   // 128 rows x 104 bf16, stride 208B (conflict-free, no swizzle)
  __shared__ char Bl[112 * 208];
  const int t = threadIdx.x, rowbase = blockIdx.x * 128;
  const int lane = t & 63, wv = t >> 6, lr = lane & 15, lg = lane >> 4;
  const f32x4 fz = {0.f, 0.f, 0.f, 0.f};
  const s16x8 hz = {0, 0, 0, 0, 0, 0, 0, 0};
  f32x4 acc[2][7];
#pragma unroll
  for (int i = 0; i < 2; ++i)
#pragma unroll
    for (int j = 0; j < 7; ++j) acc[i][j] = fz;
  s16x8 pa[8];
  int pidx[8];

  auto idxIssue = [&](int kk) {
#pragma unroll
    for (int it = 0; it < 8; ++it) {
      int r = (t + it * 256) >> 4, gr = rowbase + r;
      pidx[it] = (gr < NPTS) ? nbr[gr * KOFF + kk] : NPTS;
    }
  };
  auto gatherIssue = [&]() {
#pragma unroll
    for (int it = 0; it < 8; ++it) {
      int c = (t + it * 256) & 15;
      pa[it] = hz;
      if (c < 13)
        pa[it] = *(const s16x8*)(src + (size_t)pidx[it] * WID + c * 8);
    }
  };
  auto writeA = [&]() {
#pragma unroll
    for (int it = 0; it < 8; ++it) {
      int task = t + it * 256, r = task >> 4, c = task & 15;
      if (c < 13) *(s16x8*)(Al + r * 208 + c * 16) = pa[it];
    }
  };
  auto stageB = [&](int k) {
    s16x8 bb[6];
#pragma unroll
    for (int it = 0; it < 6; ++it) {
      int task = t + it * 256;
      if (task < 1456) {
        int r = task / 13, c = task - 13 * r;
        bb[it] = *(const s16x8*)(wct + ((size_t)k * 112 + r) * WID + c * 8);
      }
    }
#pragma unroll
    for (int it = 0; it < 6; ++it) {
      int task = t + it * 256;
      if (task < 1456) {
        int r = task / 13, c = task - 13 * r;
        *(s16x8*)(Bl + r * 208 + c * 16) = bb[it];
      }
    }
  };
  auto compute = [&]() {
#pragma unroll
    for (int kc = 0; kc < 3; ++kc) {
      int co = kc * 64 + lg * 16;
      s16x8 a[2], b[7];
#pragma unroll
      for (int mt = 0; mt < 2; ++mt)
        a[mt] = *(const s16x8*)(Al + (wv * 32 + mt * 16 + lr) * 208 + co);
#pragma unroll
      for (int ct = 0; ct < 7; ++ct)
        b[ct] = *(const s16x8*)(Bl + (ct * 16 + lr) * 208 + co);
#pragma unroll
      for (int mt = 0; mt < 2; ++mt)
#pragma unroll
        for (int ct = 0; ct < 7; ++ct) mfma16(acc[mt][ct], a[mt], b[ct]);
    }
    { // K tail: cols 96..103 live in lg==0 slots, others zero
      s16x8 a[2], b[7];
#pragma unroll
      for (int mt = 0; mt < 2; ++mt)
        a[mt] = (lg == 0) ? *(const s16x8*)(Al + (wv * 32 + mt * 16 + lr) * 208 + 192) : hz;
#pragma unroll
      for (int ct = 0; ct < 7; ++ct)
        b[ct] = (lg == 0) ? *(const s16x8*)(Bl + (ct * 16 + lr) * 208 + 192) : hz;
#pragma unroll
      for (int mt = 0; mt < 2; ++mt)
#pragma unroll
        for (int ct = 0; ct < 7; ++ct) mfma16(acc[mt][ct], a[mt], b[ct]);
    }
  };

  idxIssue(0);
  gatherIssue();
  idxIssue(1);
  for (int k = 0; k < KOFF; ++k) {
    writeA();
    stageB(k);
    __syncthreads();
    if (k < KOFF - 1) {
      gatherIssue();
      if (k < KOFF - 2) idxIssue(k + 2);
    }
    compute();
    if (k < KOFF - 1) rawbar();
  }
  // fused column stats + store
#pragma unroll
  for (int ct = 0; ct < 7; ++ct) {
    float s = 0.f, q = 0.f;
#pragma unroll
    for (int mt = 0; mt < 2; ++mt)
#pragma unroll
      for (int j = 0; j < 4; ++j) { float v = acc[mt][ct][j]; s += v; q += v * v; }
    s += __shfl_xor(s, 16); s += __shfl_xor(s, 32);
    q += __shfl_xor(q, 16); q += __shfl_xor(q, 32);
    int cl = ct * 16 + lr;
    if (cl < WID) {
      if (lg == 0) atomicAdd(&stats[cl], s);
      else if (lg == 1) atomicAdd(&stats[WID + cl], q);
    }
  }
#pragma unroll
  for (int mt = 0; mt < 2; ++mt)
#pragma unroll
    for (int ct = 0; ct < 7; ++ct)
#pragma unroll
      for (int j = 0; j < 4; ++j) {
        int r = rowbase + wv * 32 + mt * 16 + lg * 4 + j;
        int cl = ct * 16 + lr;
        if (r < NPTS && cl < WID)
          z[(size_t)r * WID + cl] = f2bf(acc[mt][ct][j]);
      }
}

// ---------------- GEMM3: BN'd cat[N,416] @ W3 -> out[N,256] fp32 + col stats ----------------
__global__ __launch_bounds__(256, 3) void k_gemm3(const u16* __restrict__ z0,
    const u16* __restrict__ z1, const u16* __restrict__ z2, const u16* __restrict__ y1,
    const u16* __restrict__ w3t, const float* __restrict__ ST, float* __restrict__ out,
    float* __restrict__ st3) {
  __shared__ char Al[128 * 128];
  __shared__ char Bl[128 * 128];
  __shared__ float sscl[416], ssft[416];
  const int t = threadIdx.x, rowbase = blockIdx.x * 128, cb = blockIdx.y;
  const int lane = t & 63, wv = t >> 6, lr = lane & 15, lg = lane >> 4;
  const int wr = wv >> 1, wc = wv & 1;
  const f32x4 fz = {0.f, 0.f, 0.f, 0.f};
  const s16x8 hz = {0, 0, 0, 0, 0, 0, 0, 0};
  for (int i = t; i < 416; i += 256) {
    float sc, sh;
    if (i < 312) {
      int p = i / 104, c = i - p * 104;
      const float* S = ST + 1664 + p * 416;
      sc = S[208 + c]; sh = S[312 + c];
    } else { sc = ST[832 + i]; sh = ST[1248 + i]; }
    sscl[i] = sc; ssft[i] = sh;
  }
  f32x4 acc[4][4];
#pragma unroll
  for (int i = 0; i < 4; ++i)
#pragma unroll
    for (int j = 0; j < 4; ++j) acc[i][j] = fz;
  s16x8 pa[4], pb[4];

  auto issue = [&](int st) {
#pragma unroll
    for (int it = 0; it < 4; ++it) {
      int task = t + it * 256, r = task >> 3, c = task & 7;
      int gr = rowbase + r, gc = st * 8 + c;
      pa[it] = hz;
      if (gr < NPTS && gc < 52) {
        int p = gc / 13, cc8 = (gc - p * 13) * 8;
        const u16* s = (p == 0) ? z0 + (size_t)gr * WID + cc8
                     : (p == 1) ? z1 + (size_t)gr * WID + cc8
                     : (p == 2) ? z2 + (size_t)gr * WID + cc8
                                : y1 + (size_t)gr * WSC + 312 + cc8;
        pa[it] = *(const s16x8*)s;
      }
      int gk = st * 64 + c * 8;
      pb[it] = hz;
      if (gk < WSC) pb[it] = *(const s16x8*)(w3t + (size_t)(cb * 128 + r) * WSC + gk);
    }
  };
  auto writeT = [&](int st) {
#pragma unroll
    for (int it = 0; it < 4; ++it) {
      int task = t + it * 256, r = task >> 3, c = task & 7;
      int gr = rowbase + r, gc = st * 8 + c;
      s16x8 h = hz;
      if (gr < NPTS && gc < 52) {
        int p = gc / 13;
        int colb = p * WID + (gc - p * 13) * 8;
#pragma unroll
        for (int j = 0; j < 8; ++j) {
          float f = fmaxf(bf2f((u16)pa[it][j]) * sscl[colb + j] + ssft[colb + j], 0.f);
          h[j] = (short)f2bf(f);
        }
      }
      *(s16x8*)(Al + ((r * 128 + c * 16) ^ ((r & 7) << 4))) = h;
      *(s16x8*)(Bl + ((r * 128 + c * 16) ^ ((r & 7) << 4))) = pb[it];
    }
  };
  auto compute = [&]() {
#pragma unroll
    for (int kc = 0; kc < 2; ++kc) {
      int co = kc * 64 + lg * 16;
      s16x8 a[4], b[4];
#pragma unroll
      for (int mt = 0; mt < 4; ++mt) {
        int r = wr * 64 + mt * 16 + lr;
        a[mt] = *(const s16x8*)(Al + ((r * 128 + co) ^ ((r & 7) << 4)));
      }
#pragma unroll
      for (int ct = 0; ct < 4; ++ct) {
        int r = wc * 64 + ct * 16 + lr;
        b[ct] = *(const s16x8*)(Bl + ((r * 128 + co) ^ ((r & 7) << 4)));
      }
#pragma unroll
      for (int mt = 0; mt < 4; ++mt)
#pragma unroll
        for (int ct = 0; ct < 4; ++ct) mfma16(acc[mt][ct], a[mt], b[ct]);
    }
  };

  issue(0);
  __syncthreads();  // sscl/ssft table visible
  for (int st = 0; st < 7; ++st) {
    writeT(st);
    __syncthreads();
    if (st < 6) issue(st + 1);
    compute();
    if (st < 6) rawbar();
  }
  // fused column stats + store
#pragma unroll
  for (int ct = 0; ct < 4; ++ct) {
    float s = 0.f, q = 0.f;
#pragma unroll
    for (int mt = 0; mt < 4; ++mt)
#pragma unroll
      for (int j = 0; j < 4; ++j) { float v = acc[mt][ct][j]; s += v; q += v * v; }
    s += __shfl_xor(s, 16); s += __shfl_xor(s, 32);
    q += __shfl_xor(q, 16); q += __shfl_xor(q, 32);
    int col = cb * 128 + wc * 64 + ct * 16 + lr;
    if (lg == 0) atomicAdd(&st3[col], s);
    else if (lg == 1) atomicAdd(&st3[INC + col], q);
  }
#pragma unroll
  for (int mt = 0; mt < 4; ++mt)
#pragma unroll
    for (int ct = 0; ct < 4; ++ct)
#pragma unroll
      for (int j = 0; j < 4; ++j) {
        int r = rowbase + wr * 64 + mt * 16 + lg * 4 + j;
        int col = cb * 128 + wc * 64 + ct * 16 + lr;
        if (r < NPTS) out[(size_t)r * INC + col] = acc[mt][ct][j];
      }
}

// ---------------- stats finalize ----------------
__global__ __launch_bounds__(512) void k_finstats(float* st, const float* __restrict__ g,
                                                  const float* __restrict__ b, int C) {
  int c = threadIdx.x;
  if (c < C) {
    float m = st[c] * (1.f / NPTS);
    float var = st[C + c] * (1.f / NPTS) - m * m;
    float rs = rsqrtf(var + EPSV);
    float sc = rs * g[c];
    st[2 * C + c] = sc;
    st[3 * C + c] = b[c] - m * sc;
  }
}

// ---------------- mix: SPX = [relu(bnc(Z)) +] relu(bn1(Y1 slice)) ----------------
template <int HASZ>
__global__ __launch_bounds__(256) void k_mix(const u16* __restrict__ y1, int yoff,
    const float* __restrict__ scl1, const float* __restrict__ sft1,
    const u16* __restrict__ z, const float* __restrict__ sclc, const float* __restrict__ sftc,
    u16* __restrict__ spx) {
  const int total = NPTS * 13;
  for (int i = blockIdx.x * 256 + threadIdx.x; i < total; i += gridDim.x * 256) {
    int r = i / 13, cc = i - r * 13;
    s16x8 y = *(const s16x8*)(y1 + (size_t)r * WSC + yoff + cc * 8);
    s16x8 zv;
    if (HASZ) zv = *(const s16x8*)(z + (size_t)r * WID + cc * 8);
    s16x8 o;
#pragma unroll
    for (int j = 0; j < 8; ++j) {
      int c = cc * 8 + j;
      float f = fmaxf(bf2f((u16)y[j]) * scl1[c] + sft1[c], 0.f);
      if (HASZ) f += fmaxf(bf2f((u16)zv[j]) * sclc[c] + sftc[c], 0.f);
      o[j] = (short)f2bf(f);
    }
    *(s16x8*)(spx + (size_t)r * WID + cc * 8) = o;
  }
}

// ---------------- final: out = relu(out*sc + sh + x) ----------------
__global__ __launch_bounds__(256) void k_final(float* __restrict__ y,
    const float* __restrict__ scale, const float* __restrict__ shift,
    const float* __restrict__ x) {
  const int total = NPTS * 64;
  for (int i = blockIdx.x * 256 + threadIdx.x; i < total; i += gridDim.x * 256) {
    int r = i >> 6, cc = i & 63;
    f32x4 v = *(f32x4*)(y + (size_t)r * INC + cc * 4);
    f32x4 xf = *(const f32x4*)(x + (size_t)r * INC + cc * 4);
#pragma unroll
    for (int j = 0; j < 4; ++j) {
      int c = cc * 4 + j;
      v[j] = fmaxf(v[j] * scale[c] + shift[c] + xf[j], 0.f);
    }
    *(f32x4*)(y + (size_t)r * INC + cc * 4) = v;
  }
}

// ---------------- launch ----------------
extern "C" void kernel_launch(void* const* d_in, const int* in_sizes, int n_in,
                              void* d_out, int out_size, void* d_ws, size_t ws_size,
                              hipStream_t stream) {
  const float* x  = (const float*)d_in[0];
  const int* nbr  = (const int*)d_in[1];
  const float* W1 = (const float*)d_in[2];
  const float* g1 = (const float*)d_in[3];
  const float* b1 = (const float*)d_in[4];
  const float* Wc = (const float*)d_in[5];
  const float* gc = (const float*)d_in[6];
  const float* bc = (const float*)d_in[7];
  const float* W3 = (const float*)d_in[8];
  const float* g3 = (const float*)d_in[9];
  const float* b3 = (const float*)d_in[10];
  float* out = (float*)d_out;

  char* ws = (char*)d_ws;
  size_t off = 0;
  auto alloc = [&](size_t n) {
    char* p = ws + off;
    off += (n + 255) & ~(size_t)255;
    return p;
  };
  u16* W1T = (u16*)alloc(416 * 256 * 2);
  u16* W3T = (u16*)alloc(256 * 416 * 2);
  u16* WCT = (u16*)alloc((size_t)3 * 27 * 112 * 104 * 2);
  u16* Y1  = (u16*)alloc((size_t)NPTS * WSC * 2);
  u16* Z0  = (u16*)alloc((size_t)NPTS * WID * 2);
  u16* Z1  = (u16*)alloc((size_t)NPTS * WID * 2);
  u16* Z2  = (u16*)alloc((size_t)NPTS * WID * 2);
  u16* SPX = (u16*)alloc((size_t)(NPTS + 1) * WID * 2);
  float* ST = (float*)alloc(3936 * 4);
  float* ST1  = ST;            // C=416: [sum][sumsq][scale][shift]
  float* STC0 = ST + 1664;     // C=104
  float* STC1 = ST + 2080;
  float* STC2 = ST + 2496;
  float* ST3  = ST + 2912;     // C=256

  k_prep_w1w3<<<832, 256, 0, stream>>>(W1, W3, W1T, W3T);
  k_prep_wc<<<81, 256, 0, stream>>>(Wc, WCT);
  k_init<<<16, 256, 0, stream>>>(ST, SPX + (size_t)NPTS * WID);

  k_gemm1<<<dim3(782, 4), 256, 0, stream>>>(x, W1T, Y1, ST1);
  k_finstats<<<1, 512, 0, stream>>>(ST1, g1, b1, WSC);

  const size_t WCL = (size_t)27 * 112 * WID;
  // branch 0
  k_mix<0><<<2048, 256, 0, stream>>>(Y1, 0, ST1 + 832, ST1 + 1248, nullptr, nullptr, nullptr, SPX);
  k_conv<<<782, 256, 0, stream>>>(SPX, nbr, WCT, Z0, STC0);
  k_finstats<<<1, 512, 0, stream>>>(STC0, gc, bc, WID);
  // branch 1
  k_mix<1><<<2048, 256, 0, stream>>>(Y1, 104, ST1 + 832 + 104, ST1 + 1248 + 104,
                                     Z0, STC0 + 208, STC0 + 312, SPX);
  k_conv<<<782, 256, 0, stream>>>(SPX, nbr, WCT + WCL, Z1, STC1);
  k_finstats<<<1, 512, 0, stream>>>(STC1, gc + 104, bc + 104, WID);
  // branch 2
  k_mix<1><<<2048, 256, 0, stream>>>(Y1, 208, ST1 + 832 + 208, ST1 + 1248 + 208,
                                     Z1, STC1 + 208, STC1 + 312, SPX);
  k_conv<<<782, 256, 0, stream>>>(SPX, nbr, WCT + 2 * WCL, Z2, STC2);
  k_finstats<<<1, 512, 0, stream>>>(STC2, gc + 208, bc + 208, WID);

  k_gemm3<<<dim3(782, 2), 256, 0, stream>>>(Z0, Z1, Z2, Y1, W3T, ST, out, ST3);
  k_finstats<<<1, 512, 0, stream>>>(ST3, g3, b3, INC);
  k_final<<<2048, 256, 0, stream>>>(out, ST3 + 512, ST3 + 768, x);
}

// Round 3
// 751.758 us; speedup vs baseline: 2.5218x; 2.5128x over previous
//
#include <hip/hip_runtime.h>

#define NPTS 100000
#define INC 256
#define WID 104
#define WSC 416
#define KOFF 27
#define EPSV 1e-5f

typedef unsigned short u16;
typedef float f32x4 __attribute__((ext_vector_type(4)));
typedef short s16x8 __attribute__((ext_vector_type(8)));

__device__ __forceinline__ u16 f2bf(float f) {
  unsigned u = __builtin_bit_cast(unsigned, f);
  u += 0x7FFFu + ((u >> 16) & 1u);
  return (u16)(u >> 16);
}
__device__ __forceinline__ float bf2f(u16 h) {
  unsigned u = ((unsigned)h) << 16;
  return __builtin_bit_cast(float, u);
}
__device__ __forceinline__ void mfma16(f32x4& d, s16x8 a, s16x8 b) {
  asm("v_mfma_f32_16x16x32_bf16 %0, %1, %2, %0" : "+v"(d) : "v"(a), "v"(b));
}
__device__ __forceinline__ void rawbar() {
  __builtin_amdgcn_s_barrier();
  __builtin_amdgcn_sched_barrier(0);
}

// stats region layout (floats): [8 banks][sum C][sumsq C], then [scale C][shift C]
// region sizes: C=416 -> 7488, C=104 -> 1872, C=256 -> 4608
#define ST1_OFF 0
#define STC0_OFF 7488
#define STC1_OFF 9360
#define STC2_OFF 11232
#define ST3_OFF 13104
#define ST_TOTAL 17712

// ---------------- weight prep ----------------
__global__ __launch_bounds__(256) void k_prep_w1w3(const float* __restrict__ w1,
    const float* __restrict__ w3, u16* __restrict__ w1t, u16* __restrict__ w3t) {
  int i = blockIdx.x * 256 + threadIdx.x;
  if (i < 416 * 256) {
    int n = i >> 8, k = i & 255;
    w1t[i] = f2bf(w1[(size_t)k * WSC + n]);
  } else if (i < 2 * 416 * 256) {
    int o = i - 416 * 256;
    int n = o / WSC, k = o - n * WSC;
    w3t[o] = f2bf(w3[(size_t)k * INC + n]);
  }
}

// WCT layout: [branch*27+k][112 rows=out-col (8 pad)][104 cols=k-in] bf16
__global__ __launch_bounds__(256) void k_prep_wc(const float* __restrict__ wc,
                                                 u16* __restrict__ wct) {
  __shared__ float w[WID * WID];
  int b = blockIdx.x, t = threadIdx.x;
  const float* s = wc + (size_t)b * WID * WID;
  for (int i = t; i < WID * WID; i += 256) w[i] = s[i];
  __syncthreads();
  u16* d = wct + (size_t)b * 112 * WID;
  for (int o = t; o < 112 * WID; o += 256) {
    int n = o / WID, kin = o - n * WID;
    d[o] = f2bf((n < WID) ? w[kin * WID + n] : 0.f);
  }
}

__global__ void k_init(float* __restrict__ st, u16* __restrict__ spxrow) {
  int i = blockIdx.x * 256 + threadIdx.x;
  if (i < ST_TOTAL) st[i] = 0.f;
  else if (i < ST_TOTAL + 104) spxrow[i - ST_TOTAL] = 0;
}

// ---------------- x -> bf16 ----------------
__global__ __launch_bounds__(256) void k_xbf(const float* __restrict__ x,
                                             u16* __restrict__ xb) {
  const int total = NPTS * INC / 8;
  for (int i = blockIdx.x * 256 + threadIdx.x; i < total; i += gridDim.x * 256) {
    const f32x4* s = (const f32x4*)(x + (size_t)i * 8);
    f32x4 v0 = s[0], v1 = s[1];
    s16x8 h;
#pragma unroll
    for (int j = 0; j < 4; ++j) { h[j] = (short)f2bf(v0[j]); h[4 + j] = (short)f2bf(v1[j]); }
    *(s16x8*)(xb + (size_t)i * 8) = h;
  }
}

// ---------------- GEMM1: xb[N,256] @ W1 -> Y1[N,416] bf16 raw + banked col stats ----------------
__global__ __launch_bounds__(256) void k_gemm1(const u16* __restrict__ xb,
    const u16* __restrict__ w1t, u16* __restrict__ y1, float* __restrict__ stats) {
  __shared__ char Al[128 * 128];
  __shared__ char Bl[112 * 128];
  const int t = threadIdx.x, rowbase = blockIdx.x * 128, cb = blockIdx.y;
  const int lane = t & 63, wv = t >> 6, lr = lane & 15, lg = lane >> 4;
  const f32x4 fz = {0.f, 0.f, 0.f, 0.f};
  const s16x8 hz = {0, 0, 0, 0, 0, 0, 0, 0};
  f32x4 acc[2][7];
#pragma unroll
  for (int i = 0; i < 2; ++i)
#pragma unroll
    for (int j = 0; j < 7; ++j) acc[i][j] = fz;
  s16x8 pa[4], pb[4];

  auto issue = [&](int st) {
#pragma unroll
    for (int it = 0; it < 4; ++it) {
      int task = t + it * 256, r = task >> 3, c = task & 7, gr = rowbase + r;
      pa[it] = hz;
      if (gr < NPTS) pa[it] = *(const s16x8*)(xb + (size_t)gr * INC + st * 64 + c * 8);
      pb[it] = hz;
      if (task < 832)
        pb[it] = *(const s16x8*)(w1t + (size_t)(cb * WID + r) * INC + st * 64 + c * 8);
    }
  };
  auto writeT = [&]() {
#pragma unroll
    for (int it = 0; it < 4; ++it) {
      int task = t + it * 256, r = task >> 3, c = task & 7;
      *(s16x8*)(Al + ((r * 128 + c * 16) ^ ((r & 7) << 4))) = pa[it];
      if (task < 896) *(s16x8*)(Bl + ((r * 128 + c * 16) ^ ((r & 7) << 4))) = pb[it];
    }
  };
  auto compute = [&]() {
#pragma unroll
    for (int kc = 0; kc < 2; ++kc) {
      int co = kc * 64 + lg * 16;
      s16x8 a[2], b[7];
#pragma unroll
      for (int mt = 0; mt < 2; ++mt) {
        int r = wv * 32 + mt * 16 + lr;
        a[mt] = *(const s16x8*)(Al + ((r * 128 + co) ^ ((r & 7) << 4)));
      }
#pragma unroll
      for (int ct = 0; ct < 7; ++ct) {
        int r = ct * 16 + lr;
        b[ct] = *(const s16x8*)(Bl + ((r * 128 + co) ^ ((r & 7) << 4)));
      }
#pragma unroll
      for (int mt = 0; mt < 2; ++mt)
#pragma unroll
        for (int ct = 0; ct < 7; ++ct) mfma16(acc[mt][ct], a[mt], b[ct]);
    }
  };

  issue(0);
  for (int st = 0; st < 4; ++st) {
    writeT();
    __syncthreads();
    if (st < 3) issue(st + 1);
    compute();
    if (st < 3) rawbar();
  }
  // block-level stats reduce (reuse Al), one banked atomic per column
  __syncthreads();
  float* S = (float*)Al;
#pragma unroll
  for (int ct = 0; ct < 7; ++ct) {
    float s = 0.f, q = 0.f;
#pragma unroll
    for (int mt = 0; mt < 2; ++mt)
#pragma unroll
      for (int j = 0; j < 4; ++j) { float v = acc[mt][ct][j]; s += v; q += v * v; }
    s += __shfl_xor(s, 16); s += __shfl_xor(s, 32);
    q += __shfl_xor(q, 16); q += __shfl_xor(q, 32);
    if (lane < 16) {
      S[wv * 224 + ct * 16 + lane] = s;
      S[wv * 224 + 112 + ct * 16 + lane] = q;
    }
  }
  __syncthreads();
  if (t < 224) {
    float v = S[t] + S[224 + t] + S[448 + t] + S[672 + t];
    int cl = (t < 112) ? t : t - 112;
    if (cl < WID) {
      float* base = stats + (blockIdx.x & 7) * 832;
      atomicAdd(base + ((t < 112) ? 0 : WSC) + cb * WID + cl, v);
    }
  }
  __syncthreads();
#pragma unroll
  for (int mt = 0; mt < 2; ++mt)
#pragma unroll
    for (int ct = 0; ct < 7; ++ct)
#pragma unroll
      for (int j = 0; j < 4; ++j) {
        int r = rowbase + wv * 32 + mt * 16 + lg * 4 + j;
        int cl = ct * 16 + lr;
        if (r < NPTS && cl < WID)
          y1[(size_t)r * WSC + cb * WID + cl] = f2bf(acc[mt][ct][j]);
      }
}

// ---------------- sparse conv: Z = sum_k gather(SPX)[nbr[:,k]] @ Wk, + banked stats ----------------
__global__ __launch_bounds__(256) void k_conv(const u16* __restrict__ src,
    const int* __restrict__ nbr, const u16* __restrict__ wct,
    u16* __restrict__ z, float* __restrict__ stats) {
  __shared__ char Al[128 * 208];   // 128 rows x 104 bf16, stride 208B
  __shared__ char Bl[112 * 208];
  const int t = threadIdx.x, rowbase = blockIdx.x * 128;
  const int lane = t & 63, wv = t >> 6, lr = lane & 15, lg = lane >> 4;
  const f32x4 fz = {0.f, 0.f, 0.f, 0.f};
  const s16x8 hz = {0, 0, 0, 0, 0, 0, 0, 0};
  f32x4 acc[2][7];
#pragma unroll
  for (int i = 0; i < 2; ++i)
#pragma unroll
    for (int j = 0; j < 7; ++j) acc[i][j] = fz;
  s16x8 pa[8], pb[6];
  int pidx[8];

  auto idxIssue = [&](int kk) {
#pragma unroll
    for (int it = 0; it < 8; ++it) {
      int r = (t + it * 256) >> 4, gr = rowbase + r;
      pidx[it] = (gr < NPTS) ? nbr[gr * KOFF + kk] : NPTS;
    }
  };
  auto gatherIssue = [&]() {
#pragma unroll
    for (int it = 0; it < 8; ++it) {
      int c = (t + it * 256) & 15;
      pa[it] = hz;
      if (c < 13)
        pa[it] = *(const s16x8*)(src + (size_t)pidx[it] * WID + c * 8);
    }
  };
  auto loadB = [&](int k) {
#pragma unroll
    for (int it = 0; it < 6; ++it) {
      int task = t + it * 256;
      if (task < 1456) {
        int r = task / 13, c = task - 13 * r;
        pb[it] = *(const s16x8*)(wct + ((size_t)k * 112 + r) * WID + c * 8);
      }
    }
  };
  auto writeA = [&]() {
#pragma unroll
    for (int it = 0; it < 8; ++it) {
      int task = t + it * 256, r = task >> 4, c = task & 15;
      if (c < 13) *(s16x8*)(Al + r * 208 + c * 16) = pa[it];
    }
  };
  auto writeB = [&]() {
#pragma unroll
    for (int it = 0; it < 6; ++it) {
      int task = t + it * 256;
      if (task < 1456) {
        int r = task / 13, c = task - 13 * r;
        *(s16x8*)(Bl + r * 208 + c * 16) = pb[it];
      }
    }
  };
  auto compute = [&]() {
#pragma unroll
    for (int kc = 0; kc < 3; ++kc) {
      int co = kc * 64 + lg * 16;
      s16x8 a[2], b[7];
#pragma unroll
      for (int mt = 0; mt < 2; ++mt)
        a[mt] = *(const s16x8*)(Al + (wv * 32 + mt * 16 + lr) * 208 + co);
#pragma unroll
      for (int ct = 0; ct < 7; ++ct)
        b[ct] = *(const s16x8*)(Bl + (ct * 16 + lr) * 208 + co);
#pragma unroll
      for (int mt = 0; mt < 2; ++mt)
#pragma unroll
        for (int ct = 0; ct < 7; ++ct) mfma16(acc[mt][ct], a[mt], b[ct]);
    }
    { // K tail: elements 96..103
      s16x8 a[2], b[7];
#pragma unroll
      for (int mt = 0; mt < 2; ++mt)
        a[mt] = (lg == 0) ? *(const s16x8*)(Al + (wv * 32 + mt * 16 + lr) * 208 + 192) : hz;
#pragma unroll
      for (int ct = 0; ct < 7; ++ct)
        b[ct] = (lg == 0) ? *(const s16x8*)(Bl + (ct * 16 + lr) * 208 + 192) : hz;
#pragma unroll
      for (int mt = 0; mt < 2; ++mt)
#pragma unroll
        for (int ct = 0; ct < 7; ++ct) mfma16(acc[mt][ct], a[mt], b[ct]);
    }
  };

  idxIssue(0);
  gatherIssue();
  loadB(0);
  idxIssue(1);
  for (int k = 0; k < KOFF; ++k) {
    writeA();
    writeB();
    __syncthreads();
    if (k < KOFF - 1) {
      gatherIssue();
      loadB(k + 1);
      if (k < KOFF - 2) idxIssue(k + 2);
    }
    compute();
    if (k < KOFF - 1) rawbar();
  }
  // block-level stats reduce (reuse Al), banked atomics
  __syncthreads();
  float* S = (float*)Al;
#pragma unroll
  for (int ct = 0; ct < 7; ++ct) {
    float s = 0.f, q = 0.f;
#pragma unroll
    for (int mt = 0; mt < 2; ++mt)
#pragma unroll
      for (int j = 0; j < 4; ++j) { float v = acc[mt][ct][j]; s += v; q += v * v; }
    s += __shfl_xor(s, 16); s += __shfl_xor(s, 32);
    q += __shfl_xor(q, 16); q += __shfl_xor(q, 32);
    if (lane < 16) {
      S[wv * 224 + ct * 16 + lane] = s;
      S[wv * 224 + 112 + ct * 16 + lane] = q;
    }
  }
  __syncthreads();
  if (t < 224) {
    float v = S[t] + S[224 + t] + S[448 + t] + S[672 + t];
    int cl = (t < 112) ? t : t - 112;
    if (cl < WID) {
      float* base = stats + (blockIdx.x & 7) * 208;
      atomicAdd(base + ((t < 112) ? 0 : WID) + cl, v);
    }
  }
  __syncthreads();
#pragma unroll
  for (int mt = 0; mt < 2; ++mt)
#pragma unroll
    for (int ct = 0; ct < 7; ++ct)
#pragma unroll
      for (int j = 0; j < 4; ++j) {
        int r = rowbase + wv * 32 + mt * 16 + lg * 4 + j;
        int cl = ct * 16 + lr;
        if (r < NPTS && cl < WID)
          z[(size_t)r * WID + cl] = f2bf(acc[mt][ct][j]);
      }
}

// ---------------- GEMM3: BN'd cat[N,416] @ W3 -> out[N,256] fp32 + banked stats ----------------
__global__ __launch_bounds__(256) void k_gemm3(const u16* __restrict__ z0,
    const u16* __restrict__ z1, const u16* __restrict__ z2, const u16* __restrict__ y1,
    const u16* __restrict__ w3t, const float* __restrict__ ST, float* __restrict__ out,
    float* __restrict__ st3) {
  __shared__ char Al[128 * 128];
  __shared__ char Bl[128 * 128];
  __shared__ float sscl[416], ssft[416];
  const int t = threadIdx.x, rowbase = blockIdx.x * 128, cb = blockIdx.y;
  const int lane = t & 63, wv = t >> 6, lr = lane & 15, lg = lane >> 4;
  const int wr = wv >> 1, wc = wv & 1;
  const f32x4 fz = {0.f, 0.f, 0.f, 0.f};
  const s16x8 hz = {0, 0, 0, 0, 0, 0, 0, 0};
  for (int i = t; i < 416; i += 256) {
    float sc, sh;
    if (i < 312) {
      int p = i / 104, c = i - p * 104;
      const float* S = ST + STC0_OFF + p * 1872;
      sc = S[1664 + c]; sh = S[1768 + c];
    } else { sc = ST[6656 + i]; sh = ST[7072 + i]; }
    sscl[i] = sc; ssft[i] = sh;
  }
  f32x4 acc[4][4];
#pragma unroll
  for (int i = 0; i < 4; ++i)
#pragma unroll
    for (int j = 0; j < 4; ++j) acc[i][j] = fz;
  s16x8 pa[4], pb[4];

  auto issue = [&](int st) {
#pragma unroll
    for (int it = 0; it < 4; ++it) {
      int task = t + it * 256, r = task >> 3, c = task & 7;
      int gr = rowbase + r, gc = st * 8 + c;
      pa[it] = hz;
      if (gr < NPTS && gc < 52) {
        int p = gc / 13, cc8 = (gc - p * 13) * 8;
        const u16* s = (p == 0) ? z0 + (size_t)gr * WID + cc8
                     : (p == 1) ? z1 + (size_t)gr * WID + cc8
                     : (p == 2) ? z2 + (size_t)gr * WID + cc8
                                : y1 + (size_t)gr * WSC + 312 + cc8;
        pa[it] = *(const s16x8*)s;
      }
      int gk = st * 64 + c * 8;
      pb[it] = hz;
      if (gk < WSC) pb[it] = *(const s16x8*)(w3t + (size_t)(cb * 128 + r) * WSC + gk);
    }
  };
  auto writeT = [&](int st) {
#pragma unroll
    for (int it = 0; it < 4; ++it) {
      int task = t + it * 256, r = task >> 3, c = task & 7;
      int gr = rowbase + r, gc = st * 8 + c;
      s16x8 h = hz;
      if (gr < NPTS && gc < 52) {
        int p = gc / 13;
        int colb = p * WID + (gc - p * 13) * 8;
#pragma unroll
        for (int j = 0; j < 8; ++j) {
          float f = fmaxf(bf2f((u16)pa[it][j]) * sscl[colb + j] + ssft[colb + j], 0.f);
          h[j] = (short)f2bf(f);
        }
      }
      *(s16x8*)(Al + ((r * 128 + c * 16) ^ ((r & 7) << 4))) = h;
      *(s16x8*)(Bl + ((r * 128 + c * 16) ^ ((r & 7) << 4))) = pb[it];
    }
  };
  auto compute = [&]() {
#pragma unroll
    for (int kc = 0; kc < 2; ++kc) {
      int co = kc * 64 + lg * 16;
      s16x8 a[4], b[4];
#pragma unroll
      for (int mt = 0; mt < 4; ++mt) {
        int r = wr * 64 + mt * 16 + lr;
        a[mt] = *(const s16x8*)(Al + ((r * 128 + co) ^ ((r & 7) << 4)));
      }
#pragma unroll
      for (int ct = 0; ct < 4; ++ct) {
        int r = wc * 64 + ct * 16 + lr;
        b[ct] = *(const s16x8*)(Bl + ((r * 128 + co) ^ ((r & 7) << 4)));
      }
#pragma unroll
      for (int mt = 0; mt < 4; ++mt)
#pragma unroll
        for (int ct = 0; ct < 4; ++ct) mfma16(acc[mt][ct], a[mt], b[ct]);
    }
  };

  issue(0);
  __syncthreads();  // sscl/ssft visible
  for (int st = 0; st < 7; ++st) {
    writeT(st);
    __syncthreads();
    if (st < 6) issue(st + 1);
    compute();
    if (st < 6) rawbar();
  }
  // block-level stats reduce, banked atomics
  __syncthreads();
  float* S = (float*)Al;
#pragma unroll
  for (int ct = 0; ct < 4; ++ct) {
    float s = 0.f, q = 0.f;
#pragma unroll
    for (int mt = 0; mt < 4; ++mt)
#pragma unroll
      for (int j = 0; j < 4; ++j) { float v = acc[mt][ct][j]; s += v; q += v * v; }
    s += __shfl_xor(s, 16); s += __shfl_xor(s, 32);
    q += __shfl_xor(q, 16); q += __shfl_xor(q, 32);
    if (lane < 16) {
      S[wv * 128 + ct * 16 + lane] = s;
      S[wv * 128 + 64 + ct * 16 + lane] = q;
    }
  }
  __syncthreads();
  {
    float* base = st3 + (blockIdx.x & 7) * 512;
    if (t < 64) atomicAdd(base + cb * 128 + t, S[t] + S[256 + t]);
    else if (t < 128) atomicAdd(base + INC + cb * 128 + (t - 64), S[64 + t - 64] + S[320 + t - 64]);
    else if (t < 192) atomicAdd(base + cb * 128 + 64 + (t - 128), S[128 + t - 128] + S[384 + t - 128]);
    else atomicAdd(base + INC + cb * 128 + 64 + (t - 192), S[192 + t - 192] + S[448 + t - 192]);
  }
#pragma unroll
  for (int mt = 0; mt < 4; ++mt)
#pragma unroll
    for (int ct = 0; ct < 4; ++ct)
#pragma unroll
      for (int j = 0; j < 4; ++j) {
        int r = rowbase + wr * 64 + mt * 16 + lg * 4 + j;
        int col = cb * 128 + wc * 64 + ct * 16 + lr;
        if (r < NPTS) out[(size_t)r * INC + col] = acc[mt][ct][j];
      }
}

// ---------------- stats finalize: sum 8 banks -> scale/shift ----------------
__global__ __launch_bounds__(512) void k_finstats(float* st, const float* __restrict__ g,
                                                  const float* __restrict__ b, int C) {
  int c = threadIdx.x;
  if (c < C) {
    float s = 0.f, q = 0.f;
#pragma unroll
    for (int bk = 0; bk < 8; ++bk) { s += st[bk * 2 * C + c]; q += st[bk * 2 * C + C + c]; }
    float m = s * (1.f / NPTS);
    float var = q * (1.f / NPTS) - m * m;
    float rs = rsqrtf(var + EPSV);
    float sc = rs * g[c];
    st[16 * C + c] = sc;
    st[17 * C + c] = b[c] - m * sc;
  }
}

// ---------------- mix: SPX = [relu(bnc(Z)) +] relu(bn1(Y1 slice)) ----------------
template <int HASZ>
__global__ __launch_bounds__(256) void k_mix(const u16* __restrict__ y1, int yoff,
    const float* __restrict__ scl1, const float* __restrict__ sft1,
    const u16* __restrict__ z, const float* __restrict__ sclc, const float* __restrict__ sftc,
    u16* __restrict__ spx) {
  const int total = NPTS * 13;
  for (int i = blockIdx.x * 256 + threadIdx.x; i < total; i += gridDim.x * 256) {
    int r = i / 13, cc = i - r * 13;
    s16x8 y = *(const s16x8*)(y1 + (size_t)r * WSC + yoff + cc * 8);
    s16x8 zv;
    if (HASZ) zv = *(const s16x8*)(z + (size_t)r * WID + cc * 8);
    s16x8 o;
#pragma unroll
    for (int j = 0; j < 8; ++j) {
      int c = cc * 8 + j;
      float f = fmaxf(bf2f((u16)y[j]) * scl1[c] + sft1[c], 0.f);
      if (HASZ) f += fmaxf(bf2f((u16)zv[j]) * sclc[c] + sftc[c], 0.f);
      o[j] = (short)f2bf(f);
    }
    *(s16x8*)(spx + (size_t)r * WID + cc * 8) = o;
  }
}

// ---------------- final: out = relu(out*sc + sh + x) ----------------
__global__ __launch_bounds__(256) void k_final(float* __restrict__ y,
    const float* __restrict__ scale, const float* __restrict__ shift,
    const float* __restrict__ x) {
  const int total = NPTS * 64;
  for (int i = blockIdx.x * 256 + threadIdx.x; i < total; i += gridDim.x * 256) {
    int r = i >> 6, cc = i & 63;
    f32x4 v = *(f32x4*)(y + (size_t)r * INC + cc * 4);
    f32x4 xf = *(const f32x4*)(x + (size_t)r * INC + cc * 4);
#pragma unroll
    for (int j = 0; j < 4; ++j) {
      int c = cc * 4 + j;
      v[j] = fmaxf(v[j] * scale[c] + shift[c] + xf[j], 0.f);
    }
    *(f32x4*)(y + (size_t)r * INC + cc * 4) = v;
  }
}

// ---------------- launch ----------------
extern "C" void kernel_launch(void* const* d_in, const int* in_sizes, int n_in,
                              void* d_out, int out_size, void* d_ws, size_t ws_size,
                              hipStream_t stream) {
  const float* x  = (const float*)d_in[0];
  const int* nbr  = (const int*)d_in[1];
  const float* W1 = (const float*)d_in[2];
  const float* g1 = (const float*)d_in[3];
  const float* b1 = (const float*)d_in[4];
  const float* Wc = (const float*)d_in[5];
  const float* gc = (const float*)d_in[6];
  const float* bc = (const float*)d_in[7];
  const float* W3 = (const float*)d_in[8];
  const float* g3 = (const float*)d_in[9];
  const float* b3 = (const float*)d_in[10];
  float* out = (float*)d_out;

  char* ws = (char*)d_ws;
  size_t off = 0;
  auto alloc = [&](size_t n) {
    char* p = ws + off;
    off += (n + 255) & ~(size_t)255;
    return p;
  };
  u16* W1T = (u16*)alloc(416 * 256 * 2);
  u16* W3T = (u16*)alloc(256 * 416 * 2);
  u16* WCT = (u16*)alloc((size_t)3 * 27 * 112 * 104 * 2);
  u16* XB  = (u16*)alloc((size_t)NPTS * INC * 2);
  u16* Y1  = (u16*)alloc((size_t)NPTS * WSC * 2);
  u16* Z0  = (u16*)alloc((size_t)NPTS * WID * 2);
  u16* Z1  = (u16*)alloc((size_t)NPTS * WID * 2);
  u16* Z2  = (u16*)alloc((size_t)NPTS * WID * 2);
  u16* SPX = (u16*)alloc((size_t)(NPTS + 1) * WID * 2);
  float* ST = (float*)alloc(ST_TOTAL * 4);
  float* ST1  = ST + ST1_OFF;
  float* STC0 = ST + STC0_OFF;
  float* STC1 = ST + STC1_OFF;
  float* STC2 = ST + STC2_OFF;
  float* ST3  = ST + ST3_OFF;

  k_prep_w1w3<<<832, 256, 0, stream>>>(W1, W3, W1T, W3T);
  k_prep_wc<<<81, 256, 0, stream>>>(Wc, WCT);
  k_init<<<70, 256, 0, stream>>>(ST, SPX + (size_t)NPTS * WID);
  k_xbf<<<2048, 256, 0, stream>>>(x, XB);

  k_gemm1<<<dim3(782, 4), 256, 0, stream>>>(XB, W1T, Y1, ST1);
  k_finstats<<<1, 512, 0, stream>>>(ST1, g1, b1, WSC);

  const size_t WCL = (size_t)27 * 112 * WID;
  // branch 0
  k_mix<0><<<2048, 256, 0, stream>>>(Y1, 0, ST1 + 6656, ST1 + 7072, nullptr, nullptr, nullptr, SPX);
  k_conv<<<782, 256, 0, stream>>>(SPX, nbr, WCT, Z0, STC0);
  k_finstats<<<1, 512, 0, stream>>>(STC0, gc, bc, WID);
  // branch 1
  k_mix<1><<<2048, 256, 0, stream>>>(Y1, 104, ST1 + 6656 + 104, ST1 + 7072 + 104,
                                     Z0, STC0 + 1664, STC0 + 1768, SPX);
  k_conv<<<782, 256, 0, stream>>>(SPX, nbr, WCT + WCL, Z1, STC1);
  k_finstats<<<1, 512, 0, stream>>>(STC1, gc + 104, bc + 104, WID);
  // branch 2
  k_mix<1><<<2048, 256, 0, stream>>>(Y1, 208, ST1 + 6656 + 208, ST1 + 7072 + 208,
                                     Z1, STC1 + 1664, STC1 + 1768, SPX);
  k_conv<<<782, 256, 0, stream>>>(SPX, nbr, WCT + 2 * WCL, Z2, STC2);
  k_finstats<<<1, 512, 0, stream>>>(STC2, gc + 208, bc + 208, WID);

  k_gemm3<<<dim3(782, 2), 256, 0, stream>>>(Z0, Z1, Z2, Y1, W3T, ST, out, ST3);
  k_finstats<<<1, 512, 0, stream>>>(ST3, g3, b3, INC);
  k_final<<<2048, 256, 0, stream>>>(out, ST3 + 4096, ST3 + 4352, x);
}